// Round 8
// baseline (272.133 us; speedup 1.0000x reference)
//
#include <hip/hip_runtime.h>

#define B_ 2
#define S_ 2048
#define D_ 1024
#define H_ 16
#define DK_ 64

typedef __attribute__((ext_vector_type(8))) short vshort8;   // 8 x bf16 (4 VGPRs)
typedef __attribute__((ext_vector_type(4))) float vfloat4;   // MFMA C/D

// f32 -> bf16 round-to-nearest-even
static __device__ inline unsigned short f2bf(float f) {
    unsigned int x = __float_as_uint(f);
    x += 0x7fffu + ((x >> 16) & 1u);
    return (unsigned short)(x >> 16);
}
// f32 -> bf16 round-half-up (2 VALU ops; fine inside softmax, P in [0,1])
static __device__ inline unsigned short f2bf_fast(float f) {
    return (unsigned short)((__float_as_uint(f) + 0x8000u) >> 16);
}
static __device__ inline float bf2f(unsigned short u) {
    return __uint_as_float((unsigned int)u << 16);
}

// async global->LDS, 16 B per lane (m97 pattern)
typedef __attribute__((address_space(1))) const unsigned int as1_uint;
typedef __attribute__((address_space(3))) unsigned int as3_uint;
static __device__ inline void async16(const void* g, void* l) {
    __builtin_amdgcn_global_load_lds((as1_uint*)g, (as3_uint*)l, 16, 0, 0);
}

// ---------------------------------------------------------------------------
// Single cast dispatch for all 7 f32->bf16 tensors.
// Flat layout: q[0,4M) k[4M,8M) v[8M,12M) wq wk wv wo (1M each) [12M,16M).
// ---------------------------------------------------------------------------
__global__ __launch_bounds__(256) void cast_all_kernel(
    const float* __restrict__ q, const float* __restrict__ k, const float* __restrict__ v,
    const float* __restrict__ wq, const float* __restrict__ wk,
    const float* __restrict__ wv, const float* __restrict__ wo,
    unsigned short* __restrict__ xq, unsigned short* __restrict__ xk, unsigned short* __restrict__ xv,
    unsigned short* __restrict__ wqb, unsigned short* __restrict__ wkb,
    unsigned short* __restrict__ wvb, unsigned short* __restrict__ wob)
{
    long idx = ((long)blockIdx.x * 256 + threadIdx.x) * 8;
    int t22 = (int)(idx >> 22);
    const float* s;
    unsigned short* d;
    long off;
    if (t22 < 3) {
        s = (t22 == 0) ? q : (t22 == 1) ? k : v;
        d = (t22 == 0) ? xq : (t22 == 1) ? xk : xv;
        off = idx & ((1L << 22) - 1);
    } else {
        int w = (int)(idx >> 20) & 3;
        s = (w == 0) ? wq : (w == 1) ? wk : (w == 2) ? wv : wo;
        d = (w == 0) ? wqb : (w == 1) ? wkb : (w == 2) ? wvb : wob;
        off = idx & ((1L << 20) - 1);
    }
    float4 f0 = *(const float4*)(s + off);
    float4 f1 = *(const float4*)(s + off + 4);
    uint4 o;
    o.x = (unsigned int)f2bf(f0.x) | ((unsigned int)f2bf(f0.y) << 16);
    o.y = (unsigned int)f2bf(f0.z) | ((unsigned int)f2bf(f0.w) << 16);
    o.z = (unsigned int)f2bf(f1.x) | ((unsigned int)f2bf(f1.y) << 16);
    o.w = (unsigned int)f2bf(f1.z) | ((unsigned int)f2bf(f1.w) << 16);
    *(uint4*)(d + off) = o;
}

// ---------------------------------------------------------------------------
// GEMM: out[M][N] = A[M][K] @ W[N][K]^T + bias. M=4096, N=K=1024 hardcoded.
// DOUBLE-BUFFERED K-loop: prefetch tile t+1 (async16) at the TOP of iter t,
// then ds_read+MFMA on tile t, then ONE barrier. XCD swizzle: bijective
// decode of bid (8 bits) -> byS (bits 0-4), bxS (bits 5-7); bid%8 constant
// across the 32 blocks sharing 4 A-strips -> ~3 MB working set per XCD L2.
// mode 0: f32 row-major out (O-projection; slot-0 ptrs).
// mode 1: QKV. z=0/1: RMSNorm+RoPE epilogue -> (B,H,S,DK); z=2: bf16 rows.
// ---------------------------------------------------------------------------
__global__ __launch_bounds__(256) void gemm_bt_kernel(
    const unsigned short* __restrict__ A0, const unsigned short* __restrict__ A1, const unsigned short* __restrict__ A2,
    const unsigned short* __restrict__ W0, const unsigned short* __restrict__ W1, const unsigned short* __restrict__ W2,
    const float* __restrict__ bb0, const float* __restrict__ bb1, const float* __restrict__ bb2,
    unsigned short* __restrict__ o0, unsigned short* __restrict__ o1, unsigned short* __restrict__ o2,
    float* __restrict__ of,
    const float* __restrict__ nw0, const float* __restrict__ nw1,
    const float* __restrict__ cosb, const float* __restrict__ sinb,
    int mode)
{
    __shared__ unsigned short As[2][128 * 32];
    __shared__ unsigned short Ws[2][128 * 32];

    const int z = blockIdx.z;
    const unsigned short* A    = (z == 0) ? A0 : (z == 1) ? A1 : A2;
    const unsigned short* Wt   = (z == 0) ? W0 : (z == 1) ? W1 : W2;
    const float* bias          = (z == 0) ? bb0 : (z == 1) ? bb1 : bb2;

    const int tid  = threadIdx.x;
    const int wave = tid >> 6;
    const int lane = tid & 63;
    const int l15  = lane & 15;
    const int quad = lane >> 4;
    const int wm   = wave >> 1;
    const int wn   = wave & 1;

    // XCD swizzle (bijective): bid bits 0-2 = xcd, 3-4 = m-sub, 5-7 = n-block
    const int bid = blockIdx.y * 8 + blockIdx.x;
    const int byS = (bid & 7) * 4 + ((bid >> 3) & 3);   // 0..31 (M-block)
    const int bxS = bid >> 5;                           // 0..7  (N-block)
    const int m0  = byS * 128;
    const int n0  = bxS * 128;

    const int li  = lane >> 2;
    const int lj  = lane & 3;
    const int lcc = (lj ^ ((li >> 1) & 3)) * 8;
    const int c0  = wave * 2;

    const unsigned short* gA0 = A  + (long)(m0 + c0 * 16      + li) * D_ + lcc;
    const unsigned short* gA1 = A  + (long)(m0 + c0 * 16 + 16 + li) * D_ + lcc;
    const unsigned short* gW0 = Wt + (long)(n0 + c0 * 16      + li) * D_ + lcc;
    const unsigned short* gW1 = Wt + (long)(n0 + c0 * 16 + 16 + li) * D_ + lcc;
    const int st0 = c0 * 512 + lane * 8;        // chunk cA dest (elems)
    const int st1 = st0 + 512;                  // chunk cB dest

    vfloat4 acc[4][4];
    for (int rt = 0; rt < 4; rt++)
        for (int ct = 0; ct < 4; ct++) {
            vfloat4 zz = {0.f, 0.f, 0.f, 0.f};
            acc[rt][ct] = zz;
        }

    const int sw = (quad ^ ((l15 >> 1) & 3)) * 8;

    // prologue: stage k-chunk 0 into buffer 0
    async16(gA0, &As[0][st0]);
    async16(gA1, &As[0][st1]);
    async16(gW0, &Ws[0][st0]);
    async16(gW1, &Ws[0][st1]);
    __syncthreads();

    for (int t = 0; t < 32; t++) {
        const int cur = t & 1;
        if (t < 31) {                       // prefetch next chunk FIRST
            const int nxt = cur ^ 1;
            const int kn  = (t + 1) * 32;
            async16(gA0 + kn, &As[nxt][st0]);
            async16(gA1 + kn, &As[nxt][st1]);
            async16(gW0 + kn, &Ws[nxt][st0]);
            async16(gW1 + kn, &Ws[nxt][st1]);
        }

        vshort8 af[4], bf[4];
        for (int rt = 0; rt < 4; rt++)
            af[rt] = *(const vshort8*)&As[cur][(wm * 64 + rt * 16 + l15) * 32 + sw];
        for (int ct = 0; ct < 4; ct++)
            bf[ct] = *(const vshort8*)&Ws[cur][(wn * 64 + ct * 16 + l15) * 32 + sw];
        for (int rt = 0; rt < 4; rt++)
            for (int ct = 0; ct < 4; ct++)
                acc[rt][ct] = __builtin_amdgcn_mfma_f32_16x16x32_bf16(af[rt], bf[ct], acc[rt][ct], 0, 0, 0);

        __syncthreads();   // waves done with buf[cur]; prefetch drained (overlapped)
    }

    if (mode == 0) {
        for (int rt = 0; rt < 4; rt++) {
            int row = m0 + wm * 64 + rt * 16 + quad * 4;
            for (int ct = 0; ct < 4; ct++) {
                int col = n0 + wn * 64 + ct * 16 + l15;
                float bvv = bias[col];
                for (int r = 0; r < 4; r++)
                    of[(long)(row + r) * D_ + col] = acc[rt][ct][r] + bvv;
            }
        }
    } else if (z == 2) {
        for (int rt = 0; rt < 4; rt++) {
            int row = m0 + wm * 64 + rt * 16 + quad * 4;
            for (int ct = 0; ct < 4; ct++) {
                int col = n0 + wn * 64 + ct * 16 + l15;
                float bvv = bias[col];
                for (int r = 0; r < 4; r++)
                    o2[(long)(row + r) * D_ + col] = f2bf(acc[rt][ct][r] + bvv);
            }
        }
    } else {
        // fused RMSNorm + RoPE epilogue for Q (z=0) / K (z=1)
        const float* w      = (z == 0) ? nw0 : nw1;
        unsigned short* out = (z == 0) ? o0  : o1;
        const float sfac    = (z == 0) ? 0.18033688011112042f : 1.0f;  // (1/8)*log2(e)
        const int h = bxS * 2 + wn;
        float wv4[4], bv4[4];
        for (int ct = 0; ct < 4; ct++) {
            int dk = ct * 16 + l15;
            wv4[ct] = w[dk];
            bv4[ct] = bias[n0 + wn * 64 + dk];
        }
        for (int rt = 0; rt < 4; rt++) {
            for (int r = 0; r < 4; r++) {
                int row = m0 + wm * 64 + rt * 16 + quad * 4 + r;   // b*S + s
                int s = row & (S_ - 1);
                int b = row >> 11;
                float x0 = acc[rt][0][r] + bv4[0];
                float x1 = acc[rt][1][r] + bv4[1];
                float x2 = acc[rt][2][r] + bv4[2];
                float x3 = acc[rt][3][r] + bv4[3];
                float ss = (x0 * x0 + x1 * x1) + (x2 * x2 + x3 * x3);
                ss += __shfl_xor(ss, 1, 64);
                ss += __shfl_xor(ss, 2, 64);
                ss += __shfl_xor(ss, 4, 64);
                ss += __shfl_xor(ss, 8, 64);
                float rn = rsqrtf(ss * (1.0f / 64.0f) + 1e-6f);
                float n0v = x0 * rn * wv4[0];
                float n1v = x1 * rn * wv4[1];
                float n2v = x2 * rn * wv4[2];
                float n3v = x3 * rn * wv4[3];
                long csb = (long)s * DK_ + l15;
                float c0v = cosb[csb], c1v = cosb[csb + 16], c2v = cosb[csb + 32], c3v = cosb[csb + 48];
                float s0v = sinb[csb], s1v = sinb[csb + 16], s2v = sinb[csb + 32], s3v = sinb[csb + 48];
                float v0 = (n0v * c0v - n2v * s0v) * sfac;
                float v1 = (n1v * c1v - n3v * s1v) * sfac;
                float v2 = (n2v * c2v + n0v * s2v) * sfac;
                float v3 = (n3v * c3v + n1v * s3v) * sfac;
                long ob = ((long)(b * H_ + h) * S_ + s) * DK_ + l15;
                out[ob]      = f2bf(v0);
                out[ob + 16] = f2bf(v1);
                out[ob + 32] = f2bf(v2);
                out[ob + 48] = f2bf(v3);
            }
        }
    }
}

// ---------------------------------------------------------------------------
// V relayout: (B,S,D) bf16 -> (B,H,DK,S) bf16 via LDS tile.
// ---------------------------------------------------------------------------
__global__ __launch_bounds__(256) void transpose_v_kernel(
    const unsigned short* __restrict__ X,
    unsigned short* __restrict__ Vt)
{
    __shared__ unsigned short T[64][72];
    int st = blockIdx.x, bh = blockIdx.y;
    int b = bh >> 4, h = bh & 15;
    int s0 = st * 64;

    for (int it = 0; it < 2; it++) {
        int idx = threadIdx.x + it * 256;
        int r = idx >> 3;
        int c = (idx & 7) * 8;
        *(uint4*)&T[r][c] = *(const uint4*)&X[(long)(b * S_ + s0 + r) * D_ + h * 64 + c];
    }
    __syncthreads();
    for (int it = 0; it < 2; it++) {
        int idx = threadIdx.x + it * 256;
        int dk = idx >> 3;
        int ss = (idx & 7) * 8;
        unsigned short pk[8];
        for (int j = 0; j < 8; j++) pk[j] = T[ss + j][dk];
        *(uint4*)&Vt[((long)(b * H_ + h) * DK_ + dk) * S_ + s0 + ss] = *(uint4*)pk;
    }
}

// ---------------------------------------------------------------------------
// Causal flash attention (unchanged from R6): paired q-strips, LDS K/V
// double-buffer, one barrier/tile, fixed-max exp2 softmax.
// ---------------------------------------------------------------------------
__global__ __launch_bounds__(256, 2) void attn_kernel(
    const unsigned short* __restrict__ Q,   // (B*H, S, DK) bf16, pre-scaled
    const unsigned short* __restrict__ K,   // (B*H, S, DK) bf16
    const unsigned short* __restrict__ Vt,  // (B*H, DK, S) bf16
    unsigned short* __restrict__ O)         // (B, S, D) bf16
{
    __shared__ unsigned short Kbuf[2][64 * 64];
    __shared__ unsigned short Vbuf[2][64 * 64];
    __shared__ unsigned short Pscr[4][2][16 * 72];

    const int tid  = threadIdx.x;
    const int wave = tid >> 6;
    const int lane = tid & 63;
    const int l15  = lane & 15;
    const int quad = lane >> 4;
    const int qa   = blockIdx.x;          // 0..15
    const int qb   = 31 - qa;             // 16..31
    const int bh   = blockIdx.y;
    const int b    = bh >> 4;
    const int h    = bh & 15;
    const long baseQ = (long)bh * S_ * DK_;
    const long baseV = (long)bh * DK_ * S_;
    const float FM = 13.0f;

    const int rowc  = lane >> 3;
    const int slotS = ((lane & 7) ^ rowc) * 8;
    const int cA    = wave * 2, cB = wave * 2 + 1;

    const unsigned short* gK0 = K  + baseQ + (long)(cA * 8 + rowc) * DK_ + slotS;
    const unsigned short* gK1 = K  + baseQ + (long)(cB * 8 + rowc) * DK_ + slotS;
    const unsigned short* gV0 = Vt + baseV + (long)(cA * 8 + rowc) * S_ + slotS;
    const unsigned short* gV1 = Vt + baseV + (long)(cB * 8 + rowc) * S_ + slotS;
    const int ldsOffA = cA * 512 + lane * 8;
    const int ldsOffB = cB * 512 + lane * 8;

    vshort8 bqA[2], bqB[2];
    {
        int qA = qa * 64 + wave * 16 + l15;
        int qB = qb * 64 + wave * 16 + l15;
        for (int kh = 0; kh < 2; kh++) {
            bqA[kh] = *(const vshort8*)&Q[baseQ + (long)qA * DK_ + kh * 32 + quad * 8];
            bqB[kh] = *(const vshort8*)&Q[baseQ + (long)qB * DK_ + kh * 32 + quad * 8];
        }
    }

    vfloat4 OaccA[4], OaccB[4];
    for (int dt = 0; dt < 4; dt++) {
        vfloat4 zz = {0.f, 0.f, 0.f, 0.f};
        OaccA[dt] = zz; OaccB[dt] = zz;
    }
    float rsA = 0.f, rsB = 0.f;

    unsigned short* PA = &Pscr[wave][0][0];
    unsigned short* PB = &Pscr[wave][1][0];

    const int nkt = qb + 1;

    async16(gK0, &Kbuf[0][ldsOffA]);
    async16(gK1, &Kbuf[0][ldsOffB]);
    async16(gV0, &Vbuf[0][ldsOffA]);
    async16(gV1, &Vbuf[0][ldsOffB]);
    __syncthreads();

    for (int t = 0; t < nkt; t++) {
        const int cur = t & 1;
        if (t + 1 < nkt) {
            const int nxt = cur ^ 1;
            const long ko = (long)(t + 1) * 64;
            async16(gK0 + ko * DK_, &Kbuf[nxt][ldsOffA]);
            async16(gK1 + ko * DK_, &Kbuf[nxt][ldsOffB]);
            async16(gV0 + ko,       &Vbuf[nxt][ldsOffA]);
            async16(gV1 + ko,       &Vbuf[nxt][ldsOffB]);
        }

        vshort8 ak[4][2];
        for (int ct = 0; ct < 4; ct++)
            for (int kh = 0; kh < 2; kh++) {
                int r = ct * 16 + l15;
                int sl = (kh * 4 + quad) ^ (l15 & 7);
                ak[ct][kh] = *(const vshort8*)&Kbuf[cur][r * 64 + sl * 8];
            }
        vshort8 av[4][2];
        for (int dt = 0; dt < 4; dt++)
            for (int kh = 0; kh < 2; kh++) {
                int r = dt * 16 + l15;
                int sl = (kh * 4 + quad) ^ (l15 & 7);
                av[dt][kh] = *(const vshort8*)&Vbuf[cur][r * 64 + sl * 8];
            }

        const int k0 = t * 64;
        const bool actA = (t <= qa);

        if (actA) {   // ---- strip A ----
            vfloat4 sc[4];
            for (int ct = 0; ct < 4; ct++) {
                vfloat4 a = {0.f, 0.f, 0.f, 0.f};
                a = __builtin_amdgcn_mfma_f32_16x16x32_bf16(ak[ct][0], bqA[0], a, 0, 0, 0);
                a = __builtin_amdgcn_mfma_f32_16x16x32_bf16(ak[ct][1], bqA[1], a, 0, 0, 0);
                sc[ct] = a;
            }
            if (t == qa) {
                int qg = qa * 64 + wave * 16 + l15;
                for (int ct = 0; ct < 4; ct++) {
                    int kvb = k0 + ct * 16 + quad * 4;
                    for (int r = 0; r < 4; r++)
                        if (kvb + r > qg) sc[ct][r] = -1e30f;
                }
            }
            for (int ct = 0; ct < 4; ct++) {
                float p0 = exp2f(sc[ct][0] - FM);
                float p1 = exp2f(sc[ct][1] - FM);
                float p2 = exp2f(sc[ct][2] - FM);
                float p3 = exp2f(sc[ct][3] - FM);
                rsA += (p0 + p1) + (p2 + p3);
                uint2 o;
                o.x = (unsigned int)f2bf_fast(p0) | ((unsigned int)f2bf_fast(p1) << 16);
                o.y = (unsigned int)f2bf_fast(p2) | ((unsigned int)f2bf_fast(p3) << 16);
                *(uint2*)&PA[l15 * 72 + ct * 16 + quad * 4] = o;
            }
            vshort8 bp[2];
            for (int kh = 0; kh < 2; kh++)
                bp[kh] = *(const vshort8*)&PA[l15 * 72 + kh * 32 + quad * 8];
            for (int dt = 0; dt < 4; dt++) {
                OaccA[dt] = __builtin_amdgcn_mfma_f32_16x16x32_bf16(av[dt][0], bp[0], OaccA[dt], 0, 0, 0);
                OaccA[dt] = __builtin_amdgcn_mfma_f32_16x16x32_bf16(av[dt][1], bp[1], OaccA[dt], 0, 0, 0);
            }
        }

        {   // ---- strip B (always active) ----
            vfloat4 sc[4];
            for (int ct = 0; ct < 4; ct++) {
                vfloat4 a = {0.f, 0.f, 0.f, 0.f};
                a = __builtin_amdgcn_mfma_f32_16x16x32_bf16(ak[ct][0], bqB[0], a, 0, 0, 0);
                a = __builtin_amdgcn_mfma_f32_16x16x32_bf16(ak[ct][1], bqB[1], a, 0, 0, 0);
                sc[ct] = a;
            }
            if (t == nkt - 1) {
                int qg = qb * 64 + wave * 16 + l15;
                for (int ct = 0; ct < 4; ct++) {
                    int kvb = k0 + ct * 16 + quad * 4;
                    for (int r = 0; r < 4; r++)
                        if (kvb + r > qg) sc[ct][r] = -1e30f;
                }
            }
            for (int ct = 0; ct < 4; ct++) {
                float p0 = exp2f(sc[ct][0] - FM);
                float p1 = exp2f(sc[ct][1] - FM);
                float p2 = exp2f(sc[ct][2] - FM);
                float p3 = exp2f(sc[ct][3] - FM);
                rsB += (p0 + p1) + (p2 + p3);
                uint2 o;
                o.x = (unsigned int)f2bf_fast(p0) | ((unsigned int)f2bf_fast(p1) << 16);
                o.y = (unsigned int)f2bf_fast(p2) | ((unsigned int)f2bf_fast(p3) << 16);
                *(uint2*)&PB[l15 * 72 + ct * 16 + quad * 4] = o;
            }
            vshort8 bp[2];
            for (int kh = 0; kh < 2; kh++)
                bp[kh] = *(const vshort8*)&PB[l15 * 72 + kh * 32 + quad * 8];
            for (int dt = 0; dt < 4; dt++) {
                OaccB[dt] = __builtin_amdgcn_mfma_f32_16x16x32_bf16(av[dt][0], bp[0], OaccB[dt], 0, 0, 0);
                OaccB[dt] = __builtin_amdgcn_mfma_f32_16x16x32_bf16(av[dt][1], bp[1], OaccB[dt], 0, 0, 0);
            }
        }

        __syncthreads();
    }

    rsA += __shfl_xor(rsA, 16, 64);
    rsA += __shfl_xor(rsA, 32, 64);
    rsB += __shfl_xor(rsB, 16, 64);
    rsB += __shfl_xor(rsB, 32, 64);

    {
        float inv = 1.0f / rsA;
        int qg = qa * 64 + wave * 16 + l15;
        long rowbase = (long)(b * S_ + qg) * D_ + h * 64;
        for (int dt = 0; dt < 4; dt++) {
            unsigned short pk[4];
            for (int r = 0; r < 4; r++) pk[r] = f2bf(OaccA[dt][r] * inv);
            uint2 o;
            o.x = (unsigned int)pk[0] | ((unsigned int)pk[1] << 16);
            o.y = (unsigned int)pk[2] | ((unsigned int)pk[3] << 16);
            *(uint2*)&O[rowbase + dt * 16 + quad * 4] = o;
        }
    }
    {
        float inv = 1.0f / rsB;
        int qg = qb * 64 + wave * 16 + l15;
        long rowbase = (long)(b * S_ + qg) * D_ + h * 64;
        for (int dt = 0; dt < 4; dt++) {
            unsigned short pk[4];
            for (int r = 0; r < 4; r++) pk[r] = f2bf(OaccB[dt][r] * inv);
            uint2 o;
            o.x = (unsigned int)pk[0] | ((unsigned int)pk[1] << 16);
            o.y = (unsigned int)pk[2] | ((unsigned int)pk[3] << 16);
            *(uint2*)&O[rowbase + dt * 16 + quad * 4] = o;
        }
    }
}

// ---------------------------------------------------------------------------
extern "C" void kernel_launch(void* const* d_in, const int* in_sizes, int n_in,
                              void* d_out, int out_size, void* d_ws, size_t ws_size,
                              hipStream_t stream) {
    const float* q    = (const float*)d_in[0];
    const float* k    = (const float*)d_in[1];
    const float* v    = (const float*)d_in[2];
    const float* cosb = (const float*)d_in[4];
    const float* sinb = (const float*)d_in[5];
    const float* wq   = (const float*)d_in[6];
    const float* bq   = (const float*)d_in[7];
    const float* wk   = (const float*)d_in[8];
    const float* bk   = (const float*)d_in[9];
    const float* wv   = (const float*)d_in[10];
    const float* bv   = (const float*)d_in[11];
    const float* wo   = (const float*)d_in[12];
    const float* bo   = (const float*)d_in[13];
    const float* qn_w = (const float*)d_in[14];
    const float* kn_w = (const float*)d_in[15];

    const long MB = 1024 * 1024;
    char* ws = (char*)d_ws;
    unsigned short* xq   = (unsigned short*)(ws + 0 * MB);
    unsigned short* xk   = (unsigned short*)(ws + 8 * MB);
    unsigned short* xv   = (unsigned short*)(ws + 16 * MB);
    unsigned short* wqb  = (unsigned short*)(ws + 24 * MB);
    unsigned short* wkb  = (unsigned short*)(ws + 26 * MB);
    unsigned short* wvb  = (unsigned short*)(ws + 28 * MB);
    unsigned short* wob  = (unsigned short*)(ws + 30 * MB);
    unsigned short* Qn   = (unsigned short*)(ws + 32 * MB);
    unsigned short* Kn   = (unsigned short*)(ws + 40 * MB);
    unsigned short* tmpv = (unsigned short*)(ws + 48 * MB);
    unsigned short* Vtb  = (unsigned short*)(ws + 56 * MB);
    unsigned short* Ob   = (unsigned short*)(ws + 64 * MB);

    dim3 blk(256);
    cast_all_kernel<<<dim3(8192), blk, 0, stream>>>(
        q, k, v, wq, wk, wv, wo, xq, xk, xv, wqb, wkb, wvb, wob);

    // fused QKV projection + normrope epilogue (768 blocks = 3 blocks/CU)
    gemm_bt_kernel<<<dim3(8, 32, 3), blk, 0, stream>>>(
        xq, xk, xv, wqb, wkb, wvb, bq, bk, bv,
        Qn, Kn, tmpv, nullptr, qn_w, kn_w, cosb, sinb, 1);

    transpose_v_kernel<<<dim3(32, 32), blk, 0, stream>>>(tmpv, Vtb);

    attn_kernel<<<dim3(16, 32), blk, 0, stream>>>(Qn, Kn, Vtb, Ob);

    // output projection, f32 out
    gemm_bt_kernel<<<dim3(8, 32, 1), blk, 0, stream>>>(
        Ob, Ob, Ob, wob, wob, wob, bo, bo, bo,
        nullptr, nullptr, nullptr, (float*)d_out, nullptr, nullptr, nullptr, nullptr, 0);
}

// Round 9
// 242.633 us; speedup vs baseline: 1.1216x; 1.1216x over previous
//
#include <hip/hip_runtime.h>

#define B_ 2
#define S_ 2048
#define D_ 1024
#define H_ 16
#define DK_ 64

typedef __attribute__((ext_vector_type(8))) short vshort8;   // 8 x bf16 (4 VGPRs)
typedef __attribute__((ext_vector_type(4))) float vfloat4;   // MFMA C/D

// f32 -> bf16 round-to-nearest-even
static __device__ inline unsigned short f2bf(float f) {
    unsigned int x = __float_as_uint(f);
    x += 0x7fffu + ((x >> 16) & 1u);
    return (unsigned short)(x >> 16);
}
// f32 -> bf16 round-half-up (2 VALU ops; fine inside softmax, P in [0,1])
static __device__ inline unsigned short f2bf_fast(float f) {
    return (unsigned short)((__float_as_uint(f) + 0x8000u) >> 16);
}
static __device__ inline float bf2f(unsigned short u) {
    return __uint_as_float((unsigned int)u << 16);
}

// async global->LDS, 16 B per lane (m97 pattern)
typedef __attribute__((address_space(1))) const unsigned int as1_uint;
typedef __attribute__((address_space(3))) unsigned int as3_uint;
static __device__ inline void async16(const void* g, void* l) {
    __builtin_amdgcn_global_load_lds((as1_uint*)g, (as3_uint*)l, 16, 0, 0);
}

// ---------------------------------------------------------------------------
// Single cast dispatch for all 7 f32->bf16 tensors.
// ---------------------------------------------------------------------------
__global__ __launch_bounds__(256) void cast_all_kernel(
    const float* __restrict__ q, const float* __restrict__ k, const float* __restrict__ v,
    const float* __restrict__ wq, const float* __restrict__ wk,
    const float* __restrict__ wv, const float* __restrict__ wo,
    unsigned short* __restrict__ xq, unsigned short* __restrict__ xk, unsigned short* __restrict__ xv,
    unsigned short* __restrict__ wqb, unsigned short* __restrict__ wkb,
    unsigned short* __restrict__ wvb, unsigned short* __restrict__ wob)
{
    long idx = ((long)blockIdx.x * 256 + threadIdx.x) * 8;
    int t22 = (int)(idx >> 22);
    const float* s;
    unsigned short* d;
    long off;
    if (t22 < 3) {
        s = (t22 == 0) ? q : (t22 == 1) ? k : v;
        d = (t22 == 0) ? xq : (t22 == 1) ? xk : xv;
        off = idx & ((1L << 22) - 1);
    } else {
        int w = (int)(idx >> 20) & 3;
        s = (w == 0) ? wq : (w == 1) ? wk : (w == 2) ? wv : wo;
        d = (w == 0) ? wqb : (w == 1) ? wkb : (w == 2) ? wvb : wob;
        off = idx & ((1L << 20) - 1);
    }
    float4 f0 = *(const float4*)(s + off);
    float4 f1 = *(const float4*)(s + off + 4);
    uint4 o;
    o.x = (unsigned int)f2bf(f0.x) | ((unsigned int)f2bf(f0.y) << 16);
    o.y = (unsigned int)f2bf(f0.z) | ((unsigned int)f2bf(f0.w) << 16);
    o.z = (unsigned int)f2bf(f1.x) | ((unsigned int)f2bf(f1.y) << 16);
    o.w = (unsigned int)f2bf(f1.z) | ((unsigned int)f2bf(f1.w) << 16);
    *(uint4*)(d + off) = o;
}

// ---------------------------------------------------------------------------
// GEMM: out[M][N] = A[M][K] @ W[N][K]^T + bias. M=4096, N=K=1024 hardcoded.
// 128x64 tile (one head per N-block), 512 blocks/instance -> 5-6 blocks/CU
// for fused QKV (z=0..2). Double-buffered async16 staging, XOR swizzle,
// bijective XCD-friendly bid decode. Wave w owns rows [32w,32w+32).
// mode 0: f32 row-major out (O-projection; slot-0 ptrs).
// mode 1: z=0/1: RMSNorm+RoPE epilogue -> (B,H,S,DK).
//         z=2:  V with bias -> transposed (B,H,DK,S) via LDS round-trip.
// ---------------------------------------------------------------------------
__global__ __launch_bounds__(256, 5) void gemm_bt_kernel(
    const unsigned short* __restrict__ A0, const unsigned short* __restrict__ A1, const unsigned short* __restrict__ A2,
    const unsigned short* __restrict__ W0, const unsigned short* __restrict__ W1, const unsigned short* __restrict__ W2,
    const float* __restrict__ bb0, const float* __restrict__ bb1, const float* __restrict__ bb2,
    unsigned short* __restrict__ o0, unsigned short* __restrict__ o1, unsigned short* __restrict__ o2,
    float* __restrict__ of,
    const float* __restrict__ nw0, const float* __restrict__ nw1,
    const float* __restrict__ cosb, const float* __restrict__ sinb,
    int mode)
{
    // 2 x (A 8KB + W 4KB) = 24 KB; V-transpose epilogue overlays 17 KB of it
    __shared__ __align__(16) unsigned char smem[2][12288];

    const int z = blockIdx.z;
    const unsigned short* A    = (z == 0) ? A0 : (z == 1) ? A1 : A2;
    const unsigned short* Wt   = (z == 0) ? W0 : (z == 1) ? W1 : W2;
    const float* bias          = (z == 0) ? bb0 : (z == 1) ? bb1 : bb2;

    const int tid  = threadIdx.x;
    const int wave = tid >> 6;
    const int lane = tid & 63;
    const int l15  = lane & 15;
    const int quad = lane >> 4;

    // bijective decode: byS (M, 0..31) keeps bid%8 invariant per A-strip group
    const int bid = blockIdx.y * 16 + blockIdx.x;        // 0..511
    const int byS = (bid & 7) * 4 + ((bid >> 3) & 3);    // 0..31
    const int bxS = bid >> 5;                            // 0..15
    const int m0  = byS * 128;
    const int n0  = bxS * 64;

    const int li  = lane >> 2;
    const int lj  = lane & 3;
    const int lcc = (lj ^ ((li >> 1) & 3)) * 8;

    const unsigned short* gA0 = A  + (long)(m0 + wave * 32      + li) * D_ + lcc;
    const unsigned short* gA1 = A  + (long)(m0 + wave * 32 + 16 + li) * D_ + lcc;
    const unsigned short* gW0 = Wt + (long)(n0 + wave * 16      + li) * D_ + lcc;
    const int stA0 = wave * 1024 + lane * 8;   // A chunk 2w
    const int stA1 = stA0 + 512;               // A chunk 2w+1
    const int stW  = wave * 512 + lane * 8;    // W chunk w

    vfloat4 acc[2][4];
    for (int rt = 0; rt < 2; rt++)
        for (int ct = 0; ct < 4; ct++) {
            vfloat4 zz = {0.f, 0.f, 0.f, 0.f};
            acc[rt][ct] = zz;
        }

    const int sw = (quad ^ ((l15 >> 1) & 3)) * 8;

    unsigned short* As0 = (unsigned short*)&smem[0][0];
    unsigned short* As1 = (unsigned short*)&smem[1][0];
    unsigned short* Ws0 = (unsigned short*)&smem[0][8192];
    unsigned short* Ws1 = (unsigned short*)&smem[1][8192];

    async16(gA0, As0 + stA0);
    async16(gA1, As0 + stA1);
    async16(gW0, Ws0 + stW);
    __syncthreads();

    for (int t = 0; t < 32; t++) {
        const int cur = t & 1;
        unsigned short* Asc = cur ? As1 : As0;
        unsigned short* Wsc = cur ? Ws1 : Ws0;
        if (t < 31) {
            unsigned short* Asn = cur ? As0 : As1;
            unsigned short* Wsn = cur ? Ws0 : Ws1;
            const int kn = (t + 1) * 32;
            async16(gA0 + kn, Asn + stA0);
            async16(gA1 + kn, Asn + stA1);
            async16(gW0 + kn, Wsn + stW);
        }

        vshort8 af[2], bf[4];
        for (int rt = 0; rt < 2; rt++)
            af[rt] = *(const vshort8*)&Asc[(wave * 32 + rt * 16 + l15) * 32 + sw];
        for (int ct = 0; ct < 4; ct++)
            bf[ct] = *(const vshort8*)&Wsc[(ct * 16 + l15) * 32 + sw];
        for (int rt = 0; rt < 2; rt++)
            for (int ct = 0; ct < 4; ct++)
                acc[rt][ct] = __builtin_amdgcn_mfma_f32_16x16x32_bf16(af[rt], bf[ct], acc[rt][ct], 0, 0, 0);

        __syncthreads();
    }

    if (mode == 0) {
        for (int rt = 0; rt < 2; rt++) {
            int row = m0 + wave * 32 + rt * 16 + quad * 4;
            for (int ct = 0; ct < 4; ct++) {
                int col = n0 + ct * 16 + l15;
                float bvv = bias[col];
                for (int r = 0; r < 4; r++)
                    of[(long)(row + r) * D_ + col] = acc[rt][ct][r] + bvv;
            }
        }
    } else if (z == 2) {
        // V: add bias, bf16, transpose via LDS -> (B,H,DK,S)
        unsigned short* T = (unsigned short*)&smem[0][0];   // [64][136]
        float bv4[4];
        for (int ct = 0; ct < 4; ct++) bv4[ct] = bias[n0 + ct * 16 + l15];
        for (int rt = 0; rt < 2; rt++) {
            int sl0 = wave * 32 + rt * 16 + quad * 4;
            for (int ct = 0; ct < 4; ct++) {
                unsigned short pk[4];
                for (int r = 0; r < 4; r++) pk[r] = f2bf(acc[rt][ct][r] + bv4[ct]);
                uint2 o;
                o.x = (unsigned int)pk[0] | ((unsigned int)pk[1] << 16);
                o.y = (unsigned int)pk[2] | ((unsigned int)pk[3] << 16);
                *(uint2*)&T[(ct * 16 + l15) * 136 + sl0] = o;
            }
        }
        __syncthreads();
        const int dk = tid >> 2;
        const int sc = (tid & 3) * 32;
        const int b  = byS >> 4;
        const int s0 = (byS & 15) * 128;
        const unsigned short* src = &T[dk * 136 + sc];
        unsigned short* dst = o2 + (((long)(b * H_ + bxS) * DK_ + dk) * S_) + s0 + sc;
        for (int j = 0; j < 4; j++)
            *(uint4*)(dst + j * 8) = *(const uint4*)(src + j * 8);
    } else {
        // fused RMSNorm + RoPE epilogue for Q (z=0) / K (z=1); head h = bxS
        const float* w      = (z == 0) ? nw0 : nw1;
        unsigned short* out = (z == 0) ? o0  : o1;
        const float sfac    = (z == 0) ? 0.18033688011112042f : 1.0f;  // (1/8)*log2(e)
        const int h = bxS;
        float wv4[4], bv4[4];
        for (int ct = 0; ct < 4; ct++) {
            int dk = ct * 16 + l15;
            wv4[ct] = w[dk];
            bv4[ct] = bias[n0 + dk];
        }
        for (int rt = 0; rt < 2; rt++) {
            for (int r = 0; r < 4; r++) {
                int row = m0 + wave * 32 + rt * 16 + quad * 4 + r;   // b*S + s
                int s = row & (S_ - 1);
                int b = row >> 11;
                float x0 = acc[rt][0][r] + bv4[0];
                float x1 = acc[rt][1][r] + bv4[1];
                float x2 = acc[rt][2][r] + bv4[2];
                float x3 = acc[rt][3][r] + bv4[3];
                float ss = (x0 * x0 + x1 * x1) + (x2 * x2 + x3 * x3);
                ss += __shfl_xor(ss, 1, 64);
                ss += __shfl_xor(ss, 2, 64);
                ss += __shfl_xor(ss, 4, 64);
                ss += __shfl_xor(ss, 8, 64);
                float rn = rsqrtf(ss * (1.0f / 64.0f) + 1e-6f);
                float n0v = x0 * rn * wv4[0];
                float n1v = x1 * rn * wv4[1];
                float n2v = x2 * rn * wv4[2];
                float n3v = x3 * rn * wv4[3];
                long csb = (long)s * DK_ + l15;
                float c0v = cosb[csb], c1v = cosb[csb + 16], c2v = cosb[csb + 32], c3v = cosb[csb + 48];
                float s0v = sinb[csb], s1v = sinb[csb + 16], s2v = sinb[csb + 32], s3v = sinb[csb + 48];
                float v0 = (n0v * c0v - n2v * s0v) * sfac;
                float v1 = (n1v * c1v - n3v * s1v) * sfac;
                float v2 = (n2v * c2v + n0v * s2v) * sfac;
                float v3 = (n3v * c3v + n1v * s3v) * sfac;
                long ob = ((long)(b * H_ + h) * S_ + s) * DK_ + l15;
                out[ob]      = f2bf(v0);
                out[ob + 16] = f2bf(v1);
                out[ob + 32] = f2bf(v2);
                out[ob + 48] = f2bf(v3);
            }
        }
    }
}

// ---------------------------------------------------------------------------
// Causal flash attention (unchanged from R6/R8): paired q-strips, LDS K/V
// double-buffer, one barrier/tile, fixed-max exp2 softmax.
// ---------------------------------------------------------------------------
__global__ __launch_bounds__(256, 2) void attn_kernel(
    const unsigned short* __restrict__ Q,   // (B*H, S, DK) bf16, pre-scaled
    const unsigned short* __restrict__ K,   // (B*H, S, DK) bf16
    const unsigned short* __restrict__ Vt,  // (B*H, DK, S) bf16
    unsigned short* __restrict__ O)         // (B, S, D) bf16
{
    __shared__ unsigned short Kbuf[2][64 * 64];
    __shared__ unsigned short Vbuf[2][64 * 64];
    __shared__ unsigned short Pscr[4][2][16 * 72];

    const int tid  = threadIdx.x;
    const int wave = tid >> 6;
    const int lane = tid & 63;
    const int l15  = lane & 15;
    const int quad = lane >> 4;
    const int qa   = blockIdx.x;          // 0..15
    const int qb   = 31 - qa;             // 16..31
    const int bh   = blockIdx.y;
    const int b    = bh >> 4;
    const int h    = bh & 15;
    const long baseQ = (long)bh * S_ * DK_;
    const long baseV = (long)bh * DK_ * S_;
    const float FM = 13.0f;

    const int rowc  = lane >> 3;
    const int slotS = ((lane & 7) ^ rowc) * 8;
    const int cA    = wave * 2, cB = wave * 2 + 1;

    const unsigned short* gK0 = K  + baseQ + (long)(cA * 8 + rowc) * DK_ + slotS;
    const unsigned short* gK1 = K  + baseQ + (long)(cB * 8 + rowc) * DK_ + slotS;
    const unsigned short* gV0 = Vt + baseV + (long)(cA * 8 + rowc) * S_ + slotS;
    const unsigned short* gV1 = Vt + baseV + (long)(cB * 8 + rowc) * S_ + slotS;
    const int ldsOffA = cA * 512 + lane * 8;
    const int ldsOffB = cB * 512 + lane * 8;

    vshort8 bqA[2], bqB[2];
    {
        int qA = qa * 64 + wave * 16 + l15;
        int qB = qb * 64 + wave * 16 + l15;
        for (int kh = 0; kh < 2; kh++) {
            bqA[kh] = *(const vshort8*)&Q[baseQ + (long)qA * DK_ + kh * 32 + quad * 8];
            bqB[kh] = *(const vshort8*)&Q[baseQ + (long)qB * DK_ + kh * 32 + quad * 8];
        }
    }

    vfloat4 OaccA[4], OaccB[4];
    for (int dt = 0; dt < 4; dt++) {
        vfloat4 zz = {0.f, 0.f, 0.f, 0.f};
        OaccA[dt] = zz; OaccB[dt] = zz;
    }
    float rsA = 0.f, rsB = 0.f;

    unsigned short* PA = &Pscr[wave][0][0];
    unsigned short* PB = &Pscr[wave][1][0];

    const int nkt = qb + 1;

    async16(gK0, &Kbuf[0][ldsOffA]);
    async16(gK1, &Kbuf[0][ldsOffB]);
    async16(gV0, &Vbuf[0][ldsOffA]);
    async16(gV1, &Vbuf[0][ldsOffB]);
    __syncthreads();

    for (int t = 0; t < nkt; t++) {
        const int cur = t & 1;
        if (t + 1 < nkt) {
            const int nxt = cur ^ 1;
            const long ko = (long)(t + 1) * 64;
            async16(gK0 + ko * DK_, &Kbuf[nxt][ldsOffA]);
            async16(gK1 + ko * DK_, &Kbuf[nxt][ldsOffB]);
            async16(gV0 + ko,       &Vbuf[nxt][ldsOffA]);
            async16(gV1 + ko,       &Vbuf[nxt][ldsOffB]);
        }

        vshort8 ak[4][2];
        for (int ct = 0; ct < 4; ct++)
            for (int kh = 0; kh < 2; kh++) {
                int r = ct * 16 + l15;
                int sl = (kh * 4 + quad) ^ (l15 & 7);
                ak[ct][kh] = *(const vshort8*)&Kbuf[cur][r * 64 + sl * 8];
            }
        vshort8 av[4][2];
        for (int dt = 0; dt < 4; dt++)
            for (int kh = 0; kh < 2; kh++) {
                int r = dt * 16 + l15;
                int sl = (kh * 4 + quad) ^ (l15 & 7);
                av[dt][kh] = *(const vshort8*)&Vbuf[cur][r * 64 + sl * 8];
            }

        const int k0 = t * 64;
        const bool actA = (t <= qa);

        if (actA) {   // ---- strip A ----
            vfloat4 sc[4];
            for (int ct = 0; ct < 4; ct++) {
                vfloat4 a = {0.f, 0.f, 0.f, 0.f};
                a = __builtin_amdgcn_mfma_f32_16x16x32_bf16(ak[ct][0], bqA[0], a, 0, 0, 0);
                a = __builtin_amdgcn_mfma_f32_16x16x32_bf16(ak[ct][1], bqA[1], a, 0, 0, 0);
                sc[ct] = a;
            }
            if (t == qa) {
                int qg = qa * 64 + wave * 16 + l15;
                for (int ct = 0; ct < 4; ct++) {
                    int kvb = k0 + ct * 16 + quad * 4;
                    for (int r = 0; r < 4; r++)
                        if (kvb + r > qg) sc[ct][r] = -1e30f;
                }
            }
            for (int ct = 0; ct < 4; ct++) {
                float p0 = exp2f(sc[ct][0] - FM);
                float p1 = exp2f(sc[ct][1] - FM);
                float p2 = exp2f(sc[ct][2] - FM);
                float p3 = exp2f(sc[ct][3] - FM);
                rsA += (p0 + p1) + (p2 + p3);
                uint2 o;
                o.x = (unsigned int)f2bf_fast(p0) | ((unsigned int)f2bf_fast(p1) << 16);
                o.y = (unsigned int)f2bf_fast(p2) | ((unsigned int)f2bf_fast(p3) << 16);
                *(uint2*)&PA[l15 * 72 + ct * 16 + quad * 4] = o;
            }
            vshort8 bp[2];
            for (int kh = 0; kh < 2; kh++)
                bp[kh] = *(const vshort8*)&PA[l15 * 72 + kh * 32 + quad * 8];
            for (int dt = 0; dt < 4; dt++) {
                OaccA[dt] = __builtin_amdgcn_mfma_f32_16x16x32_bf16(av[dt][0], bp[0], OaccA[dt], 0, 0, 0);
                OaccA[dt] = __builtin_amdgcn_mfma_f32_16x16x32_bf16(av[dt][1], bp[1], OaccA[dt], 0, 0, 0);
            }
        }

        {   // ---- strip B (always active) ----
            vfloat4 sc[4];
            for (int ct = 0; ct < 4; ct++) {
                vfloat4 a = {0.f, 0.f, 0.f, 0.f};
                a = __builtin_amdgcn_mfma_f32_16x16x32_bf16(ak[ct][0], bqB[0], a, 0, 0, 0);
                a = __builtin_amdgcn_mfma_f32_16x16x32_bf16(ak[ct][1], bqB[1], a, 0, 0, 0);
                sc[ct] = a;
            }
            if (t == nkt - 1) {
                int qg = qb * 64 + wave * 16 + l15;
                for (int ct = 0; ct < 4; ct++) {
                    int kvb = k0 + ct * 16 + quad * 4;
                    for (int r = 0; r < 4; r++)
                        if (kvb + r > qg) sc[ct][r] = -1e30f;
                }
            }
            for (int ct = 0; ct < 4; ct++) {
                float p0 = exp2f(sc[ct][0] - FM);
                float p1 = exp2f(sc[ct][1] - FM);
                float p2 = exp2f(sc[ct][2] - FM);
                float p3 = exp2f(sc[ct][3] - FM);
                rsB += (p0 + p1) + (p2 + p3);
                uint2 o;
                o.x = (unsigned int)f2bf_fast(p0) | ((unsigned int)f2bf_fast(p1) << 16);
                o.y = (unsigned int)f2bf_fast(p2) | ((unsigned int)f2bf_fast(p3) << 16);
                *(uint2*)&PB[l15 * 72 + ct * 16 + quad * 4] = o;
            }
            vshort8 bp[2];
            for (int kh = 0; kh < 2; kh++)
                bp[kh] = *(const vshort8*)&PB[l15 * 72 + kh * 32 + quad * 8];
            for (int dt = 0; dt < 4; dt++) {
                OaccB[dt] = __builtin_amdgcn_mfma_f32_16x16x32_bf16(av[dt][0], bp[0], OaccB[dt], 0, 0, 0);
                OaccB[dt] = __builtin_amdgcn_mfma_f32_16x16x32_bf16(av[dt][1], bp[1], OaccB[dt], 0, 0, 0);
            }
        }

        __syncthreads();
    }

    rsA += __shfl_xor(rsA, 16, 64);
    rsA += __shfl_xor(rsA, 32, 64);
    rsB += __shfl_xor(rsB, 16, 64);
    rsB += __shfl_xor(rsB, 32, 64);

    {
        float inv = 1.0f / rsA;
        int qg = qa * 64 + wave * 16 + l15;
        long rowbase = (long)(b * S_ + qg) * D_ + h * 64;
        for (int dt = 0; dt < 4; dt++) {
            unsigned short pk[4];
            for (int r = 0; r < 4; r++) pk[r] = f2bf(OaccA[dt][r] * inv);
            uint2 o;
            o.x = (unsigned int)pk[0] | ((unsigned int)pk[1] << 16);
            o.y = (unsigned int)pk[2] | ((unsigned int)pk[3] << 16);
            *(uint2*)&O[rowbase + dt * 16 + quad * 4] = o;
        }
    }
    {
        float inv = 1.0f / rsB;
        int qg = qb * 64 + wave * 16 + l15;
        long rowbase = (long)(b * S_ + qg) * D_ + h * 64;
        for (int dt = 0; dt < 4; dt++) {
            unsigned short pk[4];
            for (int r = 0; r < 4; r++) pk[r] = f2bf(OaccB[dt][r] * inv);
            uint2 o;
            o.x = (unsigned int)pk[0] | ((unsigned int)pk[1] << 16);
            o.y = (unsigned int)pk[2] | ((unsigned int)pk[3] << 16);
            *(uint2*)&O[rowbase + dt * 16 + quad * 4] = o;
        }
    }
}

// ---------------------------------------------------------------------------
extern "C" void kernel_launch(void* const* d_in, const int* in_sizes, int n_in,
                              void* d_out, int out_size, void* d_ws, size_t ws_size,
                              hipStream_t stream) {
    const float* q    = (const float*)d_in[0];
    const float* k    = (const float*)d_in[1];
    const float* v    = (const float*)d_in[2];
    const float* cosb = (const float*)d_in[4];
    const float* sinb = (const float*)d_in[5];
    const float* wq   = (const float*)d_in[6];
    const float* bq   = (const float*)d_in[7];
    const float* wk   = (const float*)d_in[8];
    const float* bk   = (const float*)d_in[9];
    const float* wv   = (const float*)d_in[10];
    const float* bv   = (const float*)d_in[11];
    const float* wo   = (const float*)d_in[12];
    const float* bo   = (const float*)d_in[13];
    const float* qn_w = (const float*)d_in[14];
    const float* kn_w = (const float*)d_in[15];

    const long MB = 1024 * 1024;
    char* ws = (char*)d_ws;
    unsigned short* xq   = (unsigned short*)(ws + 0 * MB);
    unsigned short* xk   = (unsigned short*)(ws + 8 * MB);
    unsigned short* xv   = (unsigned short*)(ws + 16 * MB);
    unsigned short* wqb  = (unsigned short*)(ws + 24 * MB);
    unsigned short* wkb  = (unsigned short*)(ws + 26 * MB);
    unsigned short* wvb  = (unsigned short*)(ws + 28 * MB);
    unsigned short* wob  = (unsigned short*)(ws + 30 * MB);
    unsigned short* Qn   = (unsigned short*)(ws + 32 * MB);
    unsigned short* Kn   = (unsigned short*)(ws + 40 * MB);
    unsigned short* Vtb  = (unsigned short*)(ws + 56 * MB);
    unsigned short* Ob   = (unsigned short*)(ws + 64 * MB);

    dim3 blk(256);
    cast_all_kernel<<<dim3(8192), blk, 0, stream>>>(
        q, k, v, wq, wk, wv, wo, xq, xk, xv, wqb, wkb, wvb, wob);

    // fused QKV projection + normrope/V-transpose epilogues (1536 blocks)
    gemm_bt_kernel<<<dim3(16, 32, 3), blk, 0, stream>>>(
        xq, xk, xv, wqb, wkb, wvb, bq, bk, bv,
        Qn, Kn, Vtb, nullptr, qn_w, kn_w, cosb, sinb, 1);

    attn_kernel<<<dim3(16, 32), blk, 0, stream>>>(Qn, Kn, Vtb, Ob);

    // output projection, f32 out (512 blocks)
    gemm_bt_kernel<<<dim3(16, 32, 1), blk, 0, stream>>>(
        Ob, Ob, Ob, wob, wob, wob, bo, bo, bo,
        nullptr, nullptr, nullptr, (float*)d_out, nullptr, nullptr, nullptr, nullptr, 0);
}